// Round 1
// 238.785 us; speedup vs baseline: 1.0264x; 1.0264x over previous
//
#include <hip/hip_runtime.h>

#define T_DIM 512
#define B_DIM 4096
#define L_DIM 4
#define LOG2E 1.44269504088896f

typedef float f4 __attribute__((ext_vector_type(4)));

// DPP move with compile-time ctrl (bound_ctrl=1: OOB lanes read 0).
template <int CTRL>
__device__ __forceinline__ float dpp_mov(float v) {
  int r = __builtin_amdgcn_update_dpp(0, __builtin_bit_cast(int, v), CTRL, 0xf, 0xf, true);
  return __builtin_bit_cast(float, r);
}
template <int CTRL>
__device__ __forceinline__ float qp_add(float v) { return v + dpp_mov<CTRL>(v); }

// Volatile global load: cannot be sunk/dropped; result pinned in VGPRs.
__device__ __forceinline__ void ld_f4(f4& dst, unsigned voff, const f4* base) {
  asm volatile("global_load_dwordx4 %0, %1, %2"
               : "=v"(dst) : "v"(voff), "s"(base) : "memory");
}
// Wait for ALL outstanding VMEM (loads and store-acks). Conservative on
// purpose: fine-grained vmcnt(N) over a mixed load/store queue was
// timing-dependent (replay divergence). Ring values are in/out so consumers
// cannot be hoisted above the wait.
__device__ __forceinline__ void wait_ring(f4* buf) {
  asm volatile("s_waitcnt vmcnt(0)"
               : "+v"(buf[0]), "+v"(buf[1]), "+v"(buf[2]), "+v"(buf[3]),
                 "+v"(buf[4]), "+v"(buf[5]), "+v"(buf[6]), "+v"(buf[7])
               :: "memory");
}

// ---------------- gate-split layer-skewed fused LSTM -------------------------
// 65536 threads = 1024 waves (4 waves/CU, one per SIMD).
// lane = 16*c + 4*l + g: block's chain c (one chain per 16-lane row), layer l,
// gate g. Skew: quad (c,l) is at time t = k - l; h_{l-1}(t) arrives via
// row_shr:4.
//
// Layer-0 GEMV (restructured, NO LDS ops): lane (c,l,g) computes the partial
// dot of gate g over x chunk [4l..4l+3]. Row reduction over the four l-lanes
// (stride 4 within the 16-lane row) is two DPP add-butterflies
// (row_ror:4 + row_ror:8) — every lane ends with its own gate-g full dot D.
// This replaces the previous quad-butterfly + ds_bpermute route, removing the
// only LDS-latency op from the kernel. D depends only on prefetched x, so all
// 8 D's of a chunk are computed UP FRONT, off the serial h-chain.
//
// Gates: one per lane (1 exp2 + 1 rcp each); all four gates (i,f,g~,o) are
// gathered with 4 quad_perm reads so every lane computes a valid cn/hm — no
// trailing bcast DPP on the chain, and cs/h are valid in all lanes.
// All weights pre-scaled by -log2e (i,f,o) / +2log2e (g~) to feed exp2.
__global__ __launch_bounds__(64, 1) void lstm_fused(
    const float* __restrict__ x,      // [T,B,16]
    const float* __restrict__ Wih0,   // [4,16]
    const float* __restrict__ Wrest,  // [3,4]
    const float* __restrict__ Whh,    // [4,4]
    const float* __restrict__ bih, const float* __restrict__ bhh,
    float* __restrict__ out) {
  const int lane = threadIdx.x;
  const int g = lane & 3;
  const int l = (lane >> 2) & 3;
  const int c = (lane >> 4) & 3;
  const int chain = blockIdx.x * 4 + c;
  const bool l0 = (l == 0);

  const float sgo[4] = {-LOG2E, -LOG2E, 2.0f * LOG2E, -LOG2E};

  // recurrent weights for this lane's (l, g)
  const float whh  = sgo[g] * Whh[l * 4 + g];
  const float wih  = l0 ? 0.f : sgo[g] * Wrest[(l - 1) * 4 + g];
  const float base = l0 ? 0.f : sgo[g] * (bih[l * 4 + g] + bhh[l * 4 + g]);
  // layer-0 GEMV weights: lane (c,l,g) holds gate g's weights for chunk l
  f4 wx;
  {
    const f4 wv = ((const f4*)Wih0)[g * 4 + l];
    const float s = sgo[g];
    wx.x = s * wv.x; wx.y = s * wv.y; wx.z = s * wv.z; wx.w = s * wv.w;
  }
  // layer-0 bias, injected once per gate column (chunk l==0 lane)
  const float dinit = l0 ? sgo[g] * (bih[g] + bhh[g]) : 0.f;
  const float vm = (g == 2) ? -2.f : 1.f;   // v = r (sigmoid) or 1-2r (tanh)
  const float va = (g == 2) ? 1.f : 0.f;

  float* __restrict__ po = out + chain;
  float h = 0.f, cs = 0.f;
  float hsv[8];

  // x addressing: t-slice of this block's 4 chains = 256B at xb + t*262144.
  // Lane (c,l,g) reads chunk l of chain c (address depends on l, not g).
  const char* xb = (const char*)x + (size_t)blockIdx.x * 256;
  unsigned vj[8];
#pragma unroll
  for (int j = 0; j < 8; ++j)
    vj[j] = (unsigned)(c * 64 + l * 16) + (unsigned)j * 262144u;

  f4 A[8], Bq[8];

  auto load8 = [&](f4* buf, int t0) {
    const f4* p = (const f4*)(xb + (size_t)t0 * 262144);
#pragma unroll
    for (int j = 0; j < 8; ++j) ld_f4(buf[j], vj[j], p);
  };

  auto cell = [&](int k, int j, float D, bool guard) {
    float hin = dpp_mov<0x114>(h);           // row_shr:4 -> h_{l-1}(t); 0 for l=0
    float pb = l0 ? D : base;
    float gate = fmaf(whh, h, fmaf(wih, hin, pb));

    float r = __builtin_amdgcn_rcpf(1.0f + __builtin_amdgcn_exp2f(gate));
    float v = fmaf(vm, r, va);               // lane g: i,f,g~,o respectively

    float i_ = dpp_mov<0x00>(v);             // quad lane0: i
    float f_ = dpp_mov<0x55>(v);             // quad lane1: f
    float tg = dpp_mov<0xAA>(v);             // quad lane2: g~
    float o_ = dpp_mov<0xFF>(v);             // quad lane3: o
    float cn = fmaf(f_, cs, i_ * tg);        // valid in ALL lanes now
    float tcn = fmaf(-2.0f,
        __builtin_amdgcn_rcpf(1.0f + __builtin_amdgcn_exp2f(2.88539008178f * cn)), 1.0f);
    float hm = o_ * tcn;                     // valid in ALL lanes (no bcast)

    if (guard) {
      const int t = k - l;
      const bool valid = (unsigned)t < (unsigned)T_DIM;
      cs = valid ? cn : cs;
      h  = valid ? hm : h;
    } else {
      cs = cn; h = hm;
    }
    hsv[j] = hm;
  };

  // Chunk body: phase 1 computes all 8 layer-0 gate dots D[j] (depends only on
  // the already-waited ring buffer — pure VALU: 4 fma + 2 DPP-add butterflies
  // each, no LDS, no h dependence). Phase 2 runs the serial h-chain consuming
  // precomputed scalars; its per-step critical path is now just the
  // ~16-op recurrence.
  auto cells8 = [&](int k0, f4* buf, bool guard) {
    float D[8];
#pragma unroll
    for (int j = 0; j < 8; ++j) {
      const f4 xv = buf[j];
      float p = fmaf(xv.x, wx.x, fmaf(xv.y, wx.y, fmaf(xv.z, wx.z, fmaf(xv.w, wx.w, dinit))));
      p = qp_add<0x124>(p);                  // row_ror:4  -> partial pairs
      p = qp_add<0x128>(p);                  // row_ror:8  -> full gate-g dot in every lane
      D[j] = p;
    }
#pragma unroll
    for (int j = 0; j < 8; ++j) cell(k0 + j, j, D[j], guard);
  };
  auto flush = [&](int k0, int jlo, int jhi) {
    if (l == 3 && g == 0) {
#pragma unroll
      for (int j = 0; j < 8; ++j)
        if (j >= jlo && j <= jhi) po[(size_t)(k0 + j - 3) * B_DIM] = hsv[j];
    }
  };

  // Schedule (proven in prior rounds): at each chunk top wait vmcnt(0) —
  // everything it drains (prev loads + prev stores) was issued a full cells8
  // (~1000+ cy) earlier, so the wait is near-free and timing-independent.
  load8(A, 0);
  wait_ring(A);
  load8(Bq, 8);
  cells8(0, A, true);                                    // warm-up k=0..7
  wait_ring(Bq); flush(0, 3, 7);  load8(A, 16);  cells8(8, Bq, false);
  wait_ring(A);  flush(8, 0, 7);  load8(Bq, 24); cells8(16, A, false);
#pragma unroll 1
  for (int n = 3; n < 63; n += 2) {
    wait_ring(Bq); flush(8 * (n - 1), 0, 7); load8(A, 8 * (n + 1));
    cells8(8 * n, Bq, false);
    wait_ring(A);  flush(8 * n, 0, 7);       load8(Bq, 8 * (n + 2));
    cells8(8 * (n + 1), A, false);
  }
  // chunk 63 (k=504..511): Bq was loaded with t=504 in the last loop iter
  wait_ring(Bq); flush(8 * 62, 0, 7);
  cells8(504, Bq, false);
  flush(504, 0, 7);
  // drain (k=512..519): stale-but-finite xv; guard + wih/gsel mask everything
  cells8(512, Bq, true);
  flush(512, 0, 2);                                      // t=509..511

  // hn, cn: every lane of quad (c,l) holds h_l(T-1) and c_l(T-1)
  if (g == 0) {
    po[(size_t)T_DIM * B_DIM + (size_t)l * B_DIM] = h;
    po[(size_t)T_DIM * B_DIM + (size_t)L_DIM * B_DIM + (size_t)l * B_DIM] = cs;
  }
}

extern "C" void kernel_launch(void* const* d_in, const int* in_sizes, int n_in,
                              void* d_out, int out_size, void* d_ws, size_t ws_size,
                              hipStream_t stream) {
  const float* x     = (const float*)d_in[0];
  const float* Wih0  = (const float*)d_in[1];
  const float* Wrest = (const float*)d_in[2];
  const float* Whh   = (const float*)d_in[3];
  const float* bih   = (const float*)d_in[4];
  const float* bhh   = (const float*)d_in[5];
  float* out = (float*)d_out;
  lstm_fused<<<B_DIM / 4, 64, 0, stream>>>(x, Wih0, Wrest, Whh, bih, bhh, out);
}

// Round 2
// 238.175 us; speedup vs baseline: 1.0291x; 1.0026x over previous
//
#include <hip/hip_runtime.h>

#define T_DIM 512
#define B_DIM 4096
#define L_DIM 4
#define LOG2E 1.44269504088896f

typedef float f4 __attribute__((ext_vector_type(4)));

// DPP move with compile-time ctrl (bound_ctrl=1: OOB lanes read 0).
template <int CTRL>
__device__ __forceinline__ float dpp_mov(float v) {
  int r = __builtin_amdgcn_update_dpp(0, __builtin_bit_cast(int, v), CTRL, 0xf, 0xf, true);
  return __builtin_bit_cast(float, r);
}
template <int CTRL>
__device__ __forceinline__ float qp_add(float v) { return v + dpp_mov<CTRL>(v); }

// Volatile global load: cannot be sunk/dropped; result pinned in VGPRs.
__device__ __forceinline__ void ld_f4(f4& dst, unsigned voff, const f4* base) {
  asm volatile("global_load_dwordx4 %0, %1, %2"
               : "=v"(dst) : "v"(voff), "s"(base) : "memory");
}
// Wait for ALL outstanding VMEM (loads and store-acks). Ring values are
// in/out as EIGHT SEPARATE f4 REGISTER operands (not a pointer!) so the ring
// stays SROA-promotable to VGPRs. R1 post-mortem: passing the ring as f4*
// put both rings in scratch (VGPR_Count=36 < the 64 regs the rings need),
// injecting a scratch round-trip into every cell — rule #20.
__device__ __forceinline__ void wait8(f4& a0, f4& a1, f4& a2, f4& a3,
                                      f4& a4, f4& a5, f4& a6, f4& a7) {
  asm volatile("s_waitcnt vmcnt(0)"
               : "+v"(a0), "+v"(a1), "+v"(a2), "+v"(a3),
                 "+v"(a4), "+v"(a5), "+v"(a6), "+v"(a7) :: "memory");
}

// ---------------- gate-split layer-skewed fused LSTM -------------------------
// 65536 threads = 1024 waves (4 waves/CU, one per SIMD).
// lane = 16*c + 4*l + g: block's chain c (one chain per 16-lane row), layer l,
// gate g. Skew: quad (c,l) is at time t = k - l; h_{l-1}(t) arrives via
// row_shr:4.
//
// Layer-0 GEMV (no LDS ops): lane (c,l,g) computes the partial dot of gate g
// over x chunk [4l..4l+3]; reduction over the four l-lanes is two DPP
// add-butterflies (row_ror:4 + row_ror:8) — every lane ends with its own
// gate-g full dot D. D depends only on prefetched x, so all 8 D's of a chunk
// are computed up front, off the serial h-chain.
//
// Gates: one per lane (1 exp2 + 1 rcp each); all four (i,f,g~,o) gathered
// with 4 quad_perm reads so every lane computes a valid cn/hm.
// Weights pre-scaled by -log2e (i,f,o) / +2log2e (g~) to feed exp2.
//
// STORAGE RULE (this round's change): no local arrays, no pointer-passing of
// locals. Rings A0..A7/B0..B7, hs0..hs7 are named registers; all "loops" over
// them are macro-expanded. This is what keeps them out of scratch.
__global__ __launch_bounds__(64, 1) void lstm_fused(
    const float* __restrict__ x,      // [T,B,16]
    const float* __restrict__ Wih0,   // [4,16]
    const float* __restrict__ Wrest,  // [3,4]
    const float* __restrict__ Whh,    // [4,4]
    const float* __restrict__ bih, const float* __restrict__ bhh,
    float* __restrict__ out) {
  const int lane = threadIdx.x;
  const int g = lane & 3;
  const int l = (lane >> 2) & 3;
  const int c = (lane >> 4) & 3;
  const int chain = blockIdx.x * 4 + c;
  const bool l0 = (l == 0);

  // gate scale: -log2e for sigmoid gates (i,f,o), +2log2e for tanh (g~).
  auto sg = [](int i) { return (i == 2) ? 2.0f * LOG2E : -LOG2E; };

  // recurrent weights for this lane's (l, g)
  const float whh  = sg(g) * Whh[l * 4 + g];
  const float wih  = l0 ? 0.f : sg(g) * Wrest[(l - 1) * 4 + g];
  const float base = l0 ? 0.f : sg(g) * (bih[l * 4 + g] + bhh[l * 4 + g]);
  // layer-0 GEMV weights: lane (c,l,g) holds gate g's weights for chunk l
  f4 wx;
  {
    const f4 wv = ((const f4*)Wih0)[g * 4 + l];
    const float s = sg(g);
    wx.x = s * wv.x; wx.y = s * wv.y; wx.z = s * wv.z; wx.w = s * wv.w;
  }
  // layer-0 bias, injected once per gate column (chunk l==0 lane)
  const float dinit = l0 ? sg(g) * (bih[g] + bhh[g]) : 0.f;
  const float vm = (g == 2) ? -2.f : 1.f;   // v = r (sigmoid) or 1-2r (tanh)
  const float va = (g == 2) ? 1.f : 0.f;

  float* __restrict__ po = out + chain;
  float h = 0.f, cs = 0.f;
  float hs0, hs1, hs2, hs3, hs4, hs5, hs6, hs7;

  // x addressing: t-slice of this block's 4 chains = 256B at xb + t*262144.
  // Lane (c,l,g) reads chunk l of chain c (address depends on l, not g).
  const char* xb = (const char*)x + (size_t)blockIdx.x * 256;
  const unsigned voff = (unsigned)(c * 64 + l * 16);

  f4 A0, A1, A2, A3, A4, A5, A6, A7;
  f4 B0, B1, B2, B3, B4, B5, B6, B7;

#define LOAD8(R, t0)                                                        \
  do {                                                                      \
    const f4* _p = (const f4*)(xb + (size_t)(t0) * 262144);                 \
    ld_f4(R##0, voff + 0u * 262144u, _p);                                   \
    ld_f4(R##1, voff + 1u * 262144u, _p);                                   \
    ld_f4(R##2, voff + 2u * 262144u, _p);                                   \
    ld_f4(R##3, voff + 3u * 262144u, _p);                                   \
    ld_f4(R##4, voff + 4u * 262144u, _p);                                   \
    ld_f4(R##5, voff + 5u * 262144u, _p);                                   \
    ld_f4(R##6, voff + 6u * 262144u, _p);                                   \
    ld_f4(R##7, voff + 7u * 262144u, _p);                                   \
  } while (0)

#define WAITR(R) wait8(R##0, R##1, R##2, R##3, R##4, R##5, R##6, R##7)

  // layer-0 gate dot: pure VALU, no h dependence.
  auto dotD = [&](f4 xv) -> float {
    float p = fmaf(xv.x, wx.x, fmaf(xv.y, wx.y, fmaf(xv.z, wx.z, fmaf(xv.w, wx.w, dinit))));
    p = qp_add<0x124>(p);                  // row_ror:4
    p = qp_add<0x128>(p);                  // row_ror:8 -> full gate-g dot everywhere
    return p;
  };

  auto cellv = [&](int k, float D, bool guard) -> float {
    float hin = dpp_mov<0x114>(h);           // row_shr:4 -> h_{l-1}(t); 0 for l=0
    float pb = l0 ? D : base;
    float gate = fmaf(whh, h, fmaf(wih, hin, pb));

    float r = __builtin_amdgcn_rcpf(1.0f + __builtin_amdgcn_exp2f(gate));
    float v = fmaf(vm, r, va);               // lane g: i,f,g~,o respectively

    float i_ = dpp_mov<0x00>(v);             // quad lane0: i
    float f_ = dpp_mov<0x55>(v);             // quad lane1: f
    float tg = dpp_mov<0xAA>(v);             // quad lane2: g~
    float o_ = dpp_mov<0xFF>(v);             // quad lane3: o
    float cn = fmaf(f_, cs, i_ * tg);        // valid in ALL lanes
    float tcn = fmaf(-2.0f,
        __builtin_amdgcn_rcpf(1.0f + __builtin_amdgcn_exp2f(2.88539008178f * cn)), 1.0f);
    float hm = o_ * tcn;                     // valid in ALL lanes

    if (guard) {
      const int t = k - l;
      const bool valid = (unsigned)t < (unsigned)T_DIM;
      cs = valid ? cn : cs;
      h  = valid ? hm : h;
    } else {
      cs = cn; h = hm;
    }
    return hm;
  };

  // Chunk body: phase 1 computes all 8 layer-0 gate dots (depends only on the
  // already-waited ring registers); phase 2 runs the serial h-chain.
#define CELLS8(R, k0, guard)                                                \
  do {                                                                      \
    float D0_ = dotD(R##0), D1_ = dotD(R##1), D2_ = dotD(R##2),             \
          D3_ = dotD(R##3), D4_ = dotD(R##4), D5_ = dotD(R##5),             \
          D6_ = dotD(R##6), D7_ = dotD(R##7);                               \
    hs0 = cellv((k0) + 0, D0_, guard);                                      \
    hs1 = cellv((k0) + 1, D1_, guard);                                      \
    hs2 = cellv((k0) + 2, D2_, guard);                                      \
    hs3 = cellv((k0) + 3, D3_, guard);                                      \
    hs4 = cellv((k0) + 4, D4_, guard);                                      \
    hs5 = cellv((k0) + 5, D5_, guard);                                      \
    hs6 = cellv((k0) + 6, D6_, guard);                                      \
    hs7 = cellv((k0) + 7, D7_, guard);                                      \
  } while (0)

  // Store h_3(t) for t = k-3, j in [jlo, jhi] (compile-time range).
#define FLUSH(k0, jlo, jhi)                                                 \
  do {                                                                      \
    if (l == 3 && g == 0) {                                                 \
      if (0 >= (jlo) && 0 <= (jhi)) po[(size_t)((k0) + 0 - 3) * B_DIM] = hs0; \
      if (1 >= (jlo) && 1 <= (jhi)) po[(size_t)((k0) + 1 - 3) * B_DIM] = hs1; \
      if (2 >= (jlo) && 2 <= (jhi)) po[(size_t)((k0) + 2 - 3) * B_DIM] = hs2; \
      if (3 >= (jlo) && 3 <= (jhi)) po[(size_t)((k0) + 3 - 3) * B_DIM] = hs3; \
      if (4 >= (jlo) && 4 <= (jhi)) po[(size_t)((k0) + 4 - 3) * B_DIM] = hs4; \
      if (5 >= (jlo) && 5 <= (jhi)) po[(size_t)((k0) + 5 - 3) * B_DIM] = hs5; \
      if (6 >= (jlo) && 6 <= (jhi)) po[(size_t)((k0) + 6 - 3) * B_DIM] = hs6; \
      if (7 >= (jlo) && 7 <= (jhi)) po[(size_t)((k0) + 7 - 3) * B_DIM] = hs7; \
    }                                                                       \
  } while (0)

  // Schedule (proven in prior rounds): at each chunk top wait vmcnt(0) —
  // everything it drains (prev loads + prev stores) was issued a full CELLS8
  // earlier, so the wait is near-free and timing-independent.
  LOAD8(A, 0);
  WAITR(A);
  LOAD8(B, 8);
  CELLS8(A, 0, true);                                    // warm-up k=0..7
  WAITR(B); FLUSH(0, 3, 7);  LOAD8(A, 16);  CELLS8(B, 8, false);
  WAITR(A); FLUSH(8, 0, 7);  LOAD8(B, 24);  CELLS8(A, 16, false);
#pragma unroll 1
  for (int n = 3; n < 63; n += 2) {
    WAITR(B); FLUSH(8 * (n - 1), 0, 7); LOAD8(A, 8 * (n + 1));
    CELLS8(B, 8 * n, false);
    WAITR(A); FLUSH(8 * n, 0, 7);       LOAD8(B, 8 * (n + 2));
    CELLS8(A, 8 * (n + 1), false);
  }
  // chunk 63 (k=504..511): B was loaded with t=504 in the last loop iter
  WAITR(B); FLUSH(8 * 62, 0, 7);
  CELLS8(B, 504, false);
  FLUSH(504, 0, 7);
  // drain (k=512..519): stale-but-finite xv; guard + wih/gsel mask everything
  CELLS8(B, 512, true);
  FLUSH(512, 0, 2);                                      // t=509..511

  // hn, cn: every lane of quad (c,l) holds h_l(T-1) and c_l(T-1)
  if (g == 0) {
    po[(size_t)T_DIM * B_DIM + (size_t)l * B_DIM] = h;
    po[(size_t)T_DIM * B_DIM + (size_t)L_DIM * B_DIM + (size_t)l * B_DIM] = cs;
  }
#undef LOAD8
#undef WAITR
#undef CELLS8
#undef FLUSH
}

extern "C" void kernel_launch(void* const* d_in, const int* in_sizes, int n_in,
                              void* d_out, int out_size, void* d_ws, size_t ws_size,
                              hipStream_t stream) {
  const float* x     = (const float*)d_in[0];
  const float* Wih0  = (const float*)d_in[1];
  const float* Wrest = (const float*)d_in[2];
  const float* Whh   = (const float*)d_in[3];
  const float* bih   = (const float*)d_in[4];
  const float* bhh   = (const float*)d_in[5];
  float* out = (float*)d_out;
  lstm_fused<<<B_DIM / 4, 64, 0, stream>>>(x, Wih0, Wrest, Whh, bih, bhh, out);
}

// Round 3
// 219.813 us; speedup vs baseline: 1.1150x; 1.0835x over previous
//
#include <hip/hip_runtime.h>

#define T_DIM 512
#define B_DIM 4096
#define L_DIM 4
#define LOG2E 1.44269504088896f

typedef float f4 __attribute__((ext_vector_type(4)));

// DPP move with compile-time ctrl (bound_ctrl=1: OOB lanes read 0).
template <int CTRL>
__device__ __forceinline__ float dpp_mov(float v) {
  int r = __builtin_amdgcn_update_dpp(0, __builtin_bit_cast(int, v), CTRL, 0xf, 0xf, true);
  return __builtin_bit_cast(float, r);
}
template <int CTRL>
__device__ __forceinline__ float qp_add(float v) { return v + dpp_mov<CTRL>(v); }

// ---------------- gate-split layer-skewed fused LSTM -------------------------
// 256 blocks x 256 threads = 1024 waves (4 waves/CU, one per SIMD).
// Within a wave, lane = 16*c + 4*l + g: chain c (16-lane row), layer l, gate g.
// Block handles 16 consecutive chains (4 waves x 4 chains) so the block's
// output stores cover full 64B lines from one CU/XCD (kills the 2x
// partial-line write amplification seen in R2's WRITE_SIZE).
//
// Skew: quad (c,l) is at time t = k - l; h_{l-1}(t) arrives via row_shr:4.
// Layer-0 GEMV: lane (c,l,g) computes the partial dot of gate g over x chunk
// [4l..4l+3]; two DPP add-butterflies (row_ror:4 + row_ror:8) give every lane
// its own gate-g full dot D. D depends only on prefetched x, so all 8 D's of
// a chunk are computed up front, off the serial h-chain.
// Gates: one per lane (1 exp2 + 1 rcp); all four (i,f,g~,o) gathered with 4
// quad_perm reads so every lane holds valid cn/hm. Weights pre-scaled by
// -log2e (i,f,o) / +2log2e (g~) to feed exp2.
//
// R3 RULE: ZERO inline asm. R0-R2 all allocated 36 VGPRs — the two 32-VGPR
// prefetch rings were provably living in scratch, round-tripping through
// memory inside the serial loop. The asm-volatile loads + 8-operand "+v"
// wait asm + "memory" clobbers were blocking promotion and scheduling.
// Plain loads let the compiler keep rings in VGPRs and emit fine-grained
// counted s_waitcnt per consumed value.
__global__ __launch_bounds__(256, 1) void lstm_fused(
    const float* __restrict__ x,      // [T,B,16]
    const float* __restrict__ Wih0,   // [4,16]
    const float* __restrict__ Wrest,  // [3,4]
    const float* __restrict__ Whh,    // [4,4]
    const float* __restrict__ bih, const float* __restrict__ bhh,
    float* __restrict__ out) {
  const int tid = threadIdx.x;
  const int lane = tid & 63;
  const int wid = tid >> 6;               // wave id in block, 0..3
  const int g = lane & 3;
  const int l = (lane >> 2) & 3;
  const int c = (lane >> 4) & 3;
  const int chain = blockIdx.x * 16 + wid * 4 + c;
  const bool l0 = (l == 0);

  // gate scale: -log2e for sigmoid gates (i,f,o), +2log2e for tanh (g~).
  auto sg = [](int i) { return (i == 2) ? 2.0f * LOG2E : -LOG2E; };

  // recurrent weights for this lane's (l, g)
  const float whh  = sg(g) * Whh[l * 4 + g];
  const float wih  = l0 ? 0.f : sg(g) * Wrest[(l - 1) * 4 + g];
  const float base = l0 ? 0.f : sg(g) * (bih[l * 4 + g] + bhh[l * 4 + g]);
  // layer-0 GEMV weights: lane (c,l,g) holds gate g's weights for chunk l
  f4 wx;
  {
    const f4 wv = ((const f4*)Wih0)[g * 4 + l];
    const float s = sg(g);
    wx.x = s * wv.x; wx.y = s * wv.y; wx.z = s * wv.z; wx.w = s * wv.w;
  }
  // layer-0 bias, injected once per gate column (chunk l==0 lane)
  const float dinit = l0 ? sg(g) * (bih[g] + bhh[g]) : 0.f;
  const float vm = (g == 2) ? -2.f : 1.f;   // v = r (sigmoid) or 1-2r (tanh)
  const float va = (g == 2) ? 1.f : 0.f;

  // x as [T][B*4] f4s; lane (c,l,g) reads f4 index chain*4 + l (g-independent
  // broadcast within the quad, 256B contiguous per wave per t).
  const f4* __restrict__ xp = (const f4*)x;
  const size_t xoff = (size_t)chain * 4 + (size_t)l;
  float* __restrict__ po = out + chain;

  float h = 0.f, cs = 0.f;
  f4 A[8], B[8];                            // constant-indexed only -> VGPRs

#define LOAD8(R, t0)                                                        \
  do {                                                                      \
    R[0] = xp[(size_t)((t0) + 0) * 16384 + xoff];                           \
    R[1] = xp[(size_t)((t0) + 1) * 16384 + xoff];                           \
    R[2] = xp[(size_t)((t0) + 2) * 16384 + xoff];                           \
    R[3] = xp[(size_t)((t0) + 3) * 16384 + xoff];                           \
    R[4] = xp[(size_t)((t0) + 4) * 16384 + xoff];                           \
    R[5] = xp[(size_t)((t0) + 5) * 16384 + xoff];                           \
    R[6] = xp[(size_t)((t0) + 6) * 16384 + xoff];                           \
    R[7] = xp[(size_t)((t0) + 7) * 16384 + xoff];                           \
  } while (0)

  // layer-0 gate dot: pure VALU, no h dependence.
  auto dotD = [&](f4 xv) -> float {
    float p = fmaf(xv.x, wx.x, fmaf(xv.y, wx.y, fmaf(xv.z, wx.z, fmaf(xv.w, wx.w, dinit))));
    p = qp_add<0x124>(p);                  // row_ror:4
    p = qp_add<0x128>(p);                  // row_ror:8 -> full gate-g dot everywhere
    return p;
  };

  auto cellv = [&](int k, float D, bool guard) {
    float hin = dpp_mov<0x114>(h);           // row_shr:4 -> h_{l-1}(t); 0 for l=0
    float pb = l0 ? D : base;
    float gate = fmaf(whh, h, fmaf(wih, hin, pb));

    float r = __builtin_amdgcn_rcpf(1.0f + __builtin_amdgcn_exp2f(gate));
    float v = fmaf(vm, r, va);               // lane g: i,f,g~,o respectively

    float i_ = dpp_mov<0x00>(v);             // quad lane0: i
    float f_ = dpp_mov<0x55>(v);             // quad lane1: f
    float tg = dpp_mov<0xAA>(v);             // quad lane2: g~
    float o_ = dpp_mov<0xFF>(v);             // quad lane3: o
    float cn = fmaf(f_, cs, i_ * tg);        // valid in ALL lanes
    float tcn = fmaf(-2.0f,
        __builtin_amdgcn_rcpf(1.0f + __builtin_amdgcn_exp2f(2.88539008178f * cn)), 1.0f);
    float hm = o_ * tcn;                     // valid in ALL lanes

    if (guard) {
      const bool valid = (unsigned)(k - l) < (unsigned)T_DIM;
      cs = valid ? cn : cs;
      h  = valid ? hm : h;
    } else {
      cs = cn; h = hm;
    }
    // store h_3(t) directly from the cell (no staging registers)
    const int t = k - 3;
    if (l == 3 && g == 0 && (unsigned)t < (unsigned)T_DIM)
      po[(size_t)t * B_DIM] = hm;
  };

  // Chunk body: phase 1 computes all 8 layer-0 gate dots (independent of h;
  // the compiler places counted vmcnt waits per consumed load); phase 2 runs
  // the serial h-chain on precomputed scalars.
#define CELLS8(R, k0, guard)                                                \
  do {                                                                      \
    float D0_ = dotD(R[0]), D1_ = dotD(R[1]), D2_ = dotD(R[2]),             \
          D3_ = dotD(R[3]), D4_ = dotD(R[4]), D5_ = dotD(R[5]),             \
          D6_ = dotD(R[6]), D7_ = dotD(R[7]);                               \
    cellv((k0) + 0, D0_, guard);                                            \
    cellv((k0) + 1, D1_, guard);                                            \
    cellv((k0) + 2, D2_, guard);                                            \
    cellv((k0) + 3, D3_, guard);                                            \
    cellv((k0) + 4, D4_, guard);                                            \
    cellv((k0) + 5, D5_, guard);                                            \
    cellv((k0) + 6, D6_, guard);                                            \
    cellv((k0) + 7, D7_, guard);                                            \
  } while (0)

  // Software pipeline in source order: issue chunk n+1's loads before running
  // chunk n's cells. One full chunk of compute sits between load issue and
  // first use; the compiler's per-value waits overlap the tail.
  LOAD8(A, 0);
  LOAD8(B, 8);
  CELLS8(A, 0, true);                                    // warm-up k=0..7
#pragma unroll 1
  for (int n = 1; n < 63; n += 2) {
    LOAD8(A, 8 * (n + 1));
    CELLS8(B, 8 * n, false);
    LOAD8(B, 8 * (n + 2));
    CELLS8(A, 8 * (n + 1), false);
  }
  // chunk 63 (k=504..511): B was loaded with t=504 in the last loop iter
  CELLS8(B, 504, false);
  // drain (k=512..519): stale-but-finite xv; guard freezes all state, stores
  // are range-checked (t=509..511 emitted here)
  CELLS8(B, 512, true);

  // hn, cn: every lane of quad (c,l) holds h_l(T-1) and c_l(T-1)
  if (g == 0) {
    po[(size_t)T_DIM * B_DIM + (size_t)l * B_DIM] = h;
    po[(size_t)T_DIM * B_DIM + (size_t)L_DIM * B_DIM + (size_t)l * B_DIM] = cs;
  }
#undef LOAD8
#undef CELLS8
}

extern "C" void kernel_launch(void* const* d_in, const int* in_sizes, int n_in,
                              void* d_out, int out_size, void* d_ws, size_t ws_size,
                              hipStream_t stream) {
  const float* x     = (const float*)d_in[0];
  const float* Wih0  = (const float*)d_in[1];
  const float* Wrest = (const float*)d_in[2];
  const float* Whh   = (const float*)d_in[3];
  const float* bih   = (const float*)d_in[4];
  const float* bhh   = (const float*)d_in[5];
  float* out = (float*)d_out;
  lstm_fused<<<B_DIM / 16, 256, 0, stream>>>(x, Wih0, Wrest, Whh, bih, bhh, out);
}

// Round 4
// 218.338 us; speedup vs baseline: 1.1226x; 1.0068x over previous
//
#include <hip/hip_runtime.h>

#define T_DIM 512
#define B_DIM 4096
#define L_DIM 4
#define LOG2E 1.44269504088896f
#define TWOLOG2E 2.88539008177793f      // 2*log2(e)
#define HALF_LN2 0.346573590279973f     // 1/(2*log2(e)) = ln(2)/2

// DPP move with compile-time ctrl (bound_ctrl=1: OOB lanes read 0).
template <int CTRL>
__device__ __forceinline__ float dpp_mov(float v) {
  int r = __builtin_amdgcn_update_dpp(0, __builtin_bit_cast(int, v), CTRL, 0xf, 0xf, true);
  return __builtin_bit_cast(float, r);
}
template <int CTRL>
__device__ __forceinline__ float qp_add(float v) { return v + dpp_mov<CTRL>(v); }

// ---------------- gate-split layer-skewed fused LSTM -------------------------
// 256 blocks x 256 threads = 1024 waves (4 waves/CU, one per SIMD).
// Within a wave, lane = 16*c + 4*l + g: chain c (16-lane row), layer l, gate g.
// Block handles 16 consecutive chains so output stores cover full 64B lines
// (R3: halved WRITE_SIZE, kept).
//
// Skew: quad (c,l) is at time t = k - l; h_{l-1}(t) arrives via row_shr:4.
//
// Layer-0 GEMV, R4 restructure: lane (c,l,g) loads ONE float x[c][4l+g]
// (wave reads a dense 256B line per t — no quad duplication). Gate-g's dot
// over chunk l is built with 3 quad_perm rotations (x values of the other
// three g-lanes) + 4 fmas; the sum over the four l-chunks is the usual two
// row_ror DPP butterflies. Every lane ends with its own gate-g full dot D.
// WHY: R3's f4-per-lane ring needed 64 VGPRs and the register-minimizing
// scheduler collapsed the software pipeline (VGPR_Count=44 < 64), exposing
// L3/HBM latency each chunk. The scalar ring needs only 16 VGPRs, so the
// prefetch distance (one full chunk, ~2000 cy) survives allocation.
//
// Gates: one per lane (1 exp2 + 1 rcp); all four (i,f,g~,o) gathered with 4
// quad_perm reads so every lane holds valid state. Weights pre-scaled by
// -log2e (i,f,o) / +2log2e (g~) to feed exp2. Cell state is tracked SCALED:
// cse = 2log2e * c (g~ lane constants pre-scaled), so tanh(c)'s exp2 consumes
// cse directly — one multiply removed from the serial chain. Unscaled c is
// reconstructed once at the end for the cn output.
__global__ __launch_bounds__(256, 1) void lstm_fused(
    const float* __restrict__ x,      // [T,B,16]
    const float* __restrict__ Wih0,   // [4,16]
    const float* __restrict__ Wrest,  // [3,4]
    const float* __restrict__ Whh,    // [4,4]
    const float* __restrict__ bih, const float* __restrict__ bhh,
    float* __restrict__ out) {
  const int tid = threadIdx.x;
  const int lane = tid & 63;
  const int wid = tid >> 6;               // wave id in block, 0..3
  const int g = lane & 3;
  const int l = (lane >> 2) & 3;
  const int c = (lane >> 4) & 3;
  const int chain = blockIdx.x * 16 + wid * 4 + c;
  const bool l0 = (l == 0);

  // gate scale: -log2e for sigmoid gates (i,f,o), +2log2e for tanh (g~).
  auto sg = [](int i) { return (i == 2) ? 2.0f * LOG2E : -LOG2E; };

  // recurrent weights for this lane's (l, g)
  const float whh  = sg(g) * Whh[l * 4 + g];
  const float wih  = l0 ? 0.f : sg(g) * Wrest[(l - 1) * 4 + g];
  const float base = l0 ? 0.f : sg(g) * (bih[l * 4 + g] + bhh[l * 4 + g]);

  // rotate-dot weights: round r multiplies x[c][4l+((g+r)&3)] (from the quad
  // rotation) by wq_r = sg(g)*Wih0[g][4l+((g+r)&3)].
  float wq0, wq1, wq2, wq3;
  {
    const float s = sg(g);
    wq0 = s * Wih0[g * 16 + 4 * l + ((g + 0) & 3)];
    wq1 = s * Wih0[g * 16 + 4 * l + ((g + 1) & 3)];
    wq2 = s * Wih0[g * 16 + 4 * l + ((g + 2) & 3)];
    wq3 = s * Wih0[g * 16 + 4 * l + ((g + 3) & 3)];
  }
  // layer-0 bias: only l==0 lanes carry it into the l-reduction (added once).
  const float dinit = l0 ? sg(g) * (bih[g] + bhh[g]) : 0.f;
  // gate post-map: sigmoid lanes v = r; tanh lane v = 2log2e*(1-2r) (scaled).
  const float vm = (g == 2) ? -2.f * TWOLOG2E : 1.f;
  const float va = (g == 2) ? TWOLOG2E : 0.f;

  // x as [T][B*16] floats; lane (c,l,g) reads element chain*16 + 4l + g.
  const float* __restrict__ xp = x + (size_t)chain * 16 + (size_t)(4 * l + g);
  float* __restrict__ po = out + chain;

  float h = 0.f, cse = 0.f;
  float A[8], B[8];                       // constant-indexed only -> VGPRs

#define LOAD8(R, t0)                                                        \
  do {                                                                      \
    R[0] = xp[(size_t)((t0) + 0) * 65536];                                  \
    R[1] = xp[(size_t)((t0) + 1) * 65536];                                  \
    R[2] = xp[(size_t)((t0) + 2) * 65536];                                  \
    R[3] = xp[(size_t)((t0) + 3) * 65536];                                  \
    R[4] = xp[(size_t)((t0) + 4) * 65536];                                  \
    R[5] = xp[(size_t)((t0) + 5) * 65536];                                  \
    R[6] = xp[(size_t)((t0) + 6) * 65536];                                  \
    R[7] = xp[(size_t)((t0) + 7) * 65536];                                  \
  } while (0)

  // layer-0 gate dot from scalar x: pure VALU, no h dependence.
  // quad_perm sel[i]=(i+r)&3: r=1 -> 0x39, r=2 -> 0x4E, r=3 -> 0x93.
  auto dotD = [&](float xv) -> float {
    float x1 = dpp_mov<0x39>(xv);
    float x2 = dpp_mov<0x4E>(xv);
    float x3 = dpp_mov<0x93>(xv);
    float p = fmaf(xv, wq0, dinit);
    p = fmaf(x1, wq1, p);
    p = fmaf(x2, wq2, p);
    p = fmaf(x3, wq3, p);
    p = qp_add<0x124>(p);                  // row_ror:4
    p = qp_add<0x128>(p);                  // row_ror:8 -> full gate-g dot everywhere
    return p;
  };

  auto cellv = [&](int k, float D, bool guard) {
    float hin = dpp_mov<0x114>(h);           // row_shr:4 -> h_{l-1}(t); 0 for l=0
    float pb = l0 ? D : base;
    float gate = fmaf(whh, h, fmaf(wih, hin, pb));

    float r = __builtin_amdgcn_rcpf(1.0f + __builtin_amdgcn_exp2f(gate));
    float v = fmaf(vm, r, va);               // lane g: i, f, 2log2e*g~, o

    float i_  = dpp_mov<0x00>(v);            // quad lane0: i
    float f_  = dpp_mov<0x55>(v);            // quad lane1: f
    float tgs = dpp_mov<0xAA>(v);            // quad lane2: 2log2e*g~
    float o_  = dpp_mov<0xFF>(v);            // quad lane3: o
    float cne = fmaf(f_, cse, i_ * tgs);     // scaled cell state, all lanes
    float tcn = fmaf(-2.0f,
        __builtin_amdgcn_rcpf(1.0f + __builtin_amdgcn_exp2f(cne)), 1.0f);
    float hm = o_ * tcn;                     // valid in ALL lanes

    if (guard) {
      const bool valid = (unsigned)(k - l) < (unsigned)T_DIM;
      cse = valid ? cne : cse;
      h   = valid ? hm : h;
    } else {
      cse = cne; h = hm;
    }
    // store h_3(t) directly from the cell
    const int t = k - 3;
    if (l == 3 && g == 0 && (unsigned)t < (unsigned)T_DIM)
      po[(size_t)t * B_DIM] = hm;
  };

  // Chunk body: phase 1 computes all 8 layer-0 gate dots (independent of h;
  // compiler places counted vmcnt waits per consumed load); phase 2 runs the
  // serial h-chain on precomputed scalars.
#define CELLS8(R, k0, guard)                                                \
  do {                                                                      \
    float D0_ = dotD(R[0]), D1_ = dotD(R[1]), D2_ = dotD(R[2]),             \
          D3_ = dotD(R[3]), D4_ = dotD(R[4]), D5_ = dotD(R[5]),             \
          D6_ = dotD(R[6]), D7_ = dotD(R[7]);                               \
    cellv((k0) + 0, D0_, guard);                                            \
    cellv((k0) + 1, D1_, guard);                                            \
    cellv((k0) + 2, D2_, guard);                                            \
    cellv((k0) + 3, D3_, guard);                                            \
    cellv((k0) + 4, D4_, guard);                                            \
    cellv((k0) + 5, D5_, guard);                                            \
    cellv((k0) + 6, D6_, guard);                                            \
    cellv((k0) + 7, D7_, guard);                                            \
  } while (0)

  // Software pipeline in source order: issue chunk n+1's loads before running
  // chunk n's cells. One full chunk of compute between load issue and first
  // use; ring is 8 VGPRs per buffer so allocation keeps it live.
  LOAD8(A, 0);
  LOAD8(B, 8);
  CELLS8(A, 0, true);                                    // warm-up k=0..7
#pragma unroll 1
  for (int n = 1; n < 63; n += 2) {
    LOAD8(A, 8 * (n + 1));
    CELLS8(B, 8 * n, false);
    LOAD8(B, 8 * (n + 2));
    CELLS8(A, 8 * (n + 1), false);
  }
  // chunk 63 (k=504..511): B was loaded with t=504 in the last loop iter
  CELLS8(B, 504, false);
  // drain (k=512..519): stale-but-finite xv; D only feeds l=0 lanes whose
  // state is guard-frozen (t>511); stores range-checked (t=509..511 emitted)
  CELLS8(B, 512, true);

  // hn, cn: every lane of quad (c,l) holds h_l(T-1) and cse_l(T-1)
  if (g == 0) {
    po[(size_t)T_DIM * B_DIM + (size_t)l * B_DIM] = h;
    po[(size_t)T_DIM * B_DIM + (size_t)L_DIM * B_DIM + (size_t)l * B_DIM] =
        cse * HALF_LN2;                     // unscale once
  }
#undef LOAD8
#undef CELLS8
}

extern "C" void kernel_launch(void* const* d_in, const int* in_sizes, int n_in,
                              void* d_out, int out_size, void* d_ws, size_t ws_size,
                              hipStream_t stream) {
  const float* x     = (const float*)d_in[0];
  const float* Wih0  = (const float*)d_in[1];
  const float* Wrest = (const float*)d_in[2];
  const float* Whh   = (const float*)d_in[3];
  const float* bih   = (const float*)d_in[4];
  const float* bhh   = (const float*)d_in[5];
  float* out = (float*)d_out;
  lstm_fused<<<B_DIM / 16, 256, 0, stream>>>(x, Wih0, Wrest, Whh, bih, bhh, out);
}